// Round 2
// baseline (419.095 us; speedup 1.0000x reference)
//
#include <hip/hip_runtime.h>

#define SCALE_F 10000.0f
#define PSF 21
#define PAD 10
#define PSF3 9261        // 21*21*21
#define NTILE_ZY 32      // 256/8
#define TZ 8
#define TY 8
#define NTILES 16384     // 16 channels * 32 * 32

// ---------------- scale pre-pass: per-PSF max -> scale[n] ----------------
__global__ __launch_bounds__(256) void psf_scale_kernel(
    const float* __restrict__ psf_raw,
    const float* __restrict__ i_val,
    float*       __restrict__ scale)
{
    const int n   = blockIdx.x;
    const int tid = threadIdx.x;
    const float* p = psf_raw + (size_t)n * PSF3;

    float m = 0.0f;
    for (int k = tid; k < PSF3; k += 256)
        m = fmaxf(m, p[k]);          // relu'd max (m starts at 0)

#pragma unroll
    for (int off = 32; off > 0; off >>= 1)
        m = fmaxf(m, __shfl_down(m, off, 64));

    __shared__ float smax[4];
    if ((tid & 63) == 0) smax[tid >> 6] = m;
    __syncthreads();
    if (tid == 0) {
        float mm = fmaxf(fmaxf(smax[0], smax[1]), fmaxf(smax[2], smax[3]));
        scale[n] = (mm > 0.0f) ? SCALE_F * fmaxf(i_val[n], 0.0f) / mm : 0.0f;
    }
}

// ---------------- binning: count ----------------
__device__ __forceinline__ void tile_range(int v0, int& lo, int& hi) {
    lo = max(v0, 0) >> 3;
    hi = min(v0 + 20, 255) >> 3;
}

__global__ __launch_bounds__(256) void count_kernel(
    const int* __restrict__ bArr, const int* __restrict__ chArr,
    const int* __restrict__ zArr, const int* __restrict__ yArr,
    int* __restrict__ cnt, int N)
{
    int n = blockIdx.x * 256 + threadIdx.x;
    if (n >= N) return;
    int c = bArr[n] * 16 + chArr[n];
    int tzlo, tzhi, tylo, tyhi;
    tile_range(zArr[n] - PAD, tzlo, tzhi);
    tile_range(yArr[n] - PAD, tylo, tyhi);
    for (int tz = tzlo; tz <= tzhi; ++tz)
        for (int ty = tylo; ty <= tyhi; ++ty)
            atomicAdd(&cnt[c * 1024 + tz * 32 + ty], 1);
}

// ---------------- binning: exclusive scan (single block) ----------------
__global__ __launch_bounds__(256) void scan_kernel(
    const int* __restrict__ cnt, int* __restrict__ off, int* __restrict__ cursor)
{
    __shared__ int s[256];
    __shared__ int base[256];
    const int t = threadIdx.x;
    const int b0 = t * 64;
    int local = 0;
    for (int i = 0; i < 64; ++i) local += cnt[b0 + i];
    s[t] = local;
    __syncthreads();
    if (t == 0) {
        int run = 0;
        for (int i = 0; i < 256; ++i) { base[i] = run; run += s[i]; }
    }
    __syncthreads();
    int run = base[t];
    for (int i = 0; i < 64; ++i) {
        int c = cnt[b0 + i];
        off[b0 + i] = run;
        cursor[b0 + i] = run;
        run += c;
    }
}

// ---------------- binning: fill ----------------
__global__ __launch_bounds__(256) void fill_kernel(
    const int* __restrict__ bArr, const int* __restrict__ chArr,
    const int* __restrict__ zArr, const int* __restrict__ yArr,
    int* __restrict__ cursor, int* __restrict__ list, int N)
{
    int n = blockIdx.x * 256 + threadIdx.x;
    if (n >= N) return;
    int c = bArr[n] * 16 + chArr[n];
    int tzlo, tzhi, tylo, tyhi;
    tile_range(zArr[n] - PAD, tzlo, tzhi);
    tile_range(yArr[n] - PAD, tylo, tyhi);
    for (int tz = tzlo; tz <= tzhi; ++tz)
        for (int ty = tylo; ty <= tyhi; ++ty) {
            int pos = atomicAdd(&cursor[c * 1024 + tz * 32 + ty], 1);
            list[pos] = n;
        }
}

// ---------------- gather: one block per (c, 8z, 8y, 64x) tile ----------------
__global__ __launch_bounds__(256) void gather_kernel(
    const float* __restrict__ psf_raw,
    const float* __restrict__ scale,
    const int* __restrict__ zArr, const int* __restrict__ yArr,
    const int* __restrict__ xArr,
    const int* __restrict__ off, const int* __restrict__ cnt,
    const int* __restrict__ list,
    float* __restrict__ out)
{
    const int tile = blockIdx.x;
    const int ty = tile & 31;
    const int tz = (tile >> 5) & 31;
    const int c  = tile >> 10;
    const int t  = threadIdx.x;
    const int x    = t & 63;
    const int ysub = t >> 6;          // wave id: 0..3
    const int zbase = tz * TZ;
    const int ybase = ty * TY;

    float acc[TZ][2] = {};

    const int o  = off[tile];
    const int cn = cnt[tile];

    for (int i = 0; i < cn; ++i) {
        const int n  = list[o + i];                 // block-uniform
        const int z0 = zArr[n] - PAD;
        const int y0 = yArr[n] - PAD;
        const int x0 = xArr[n] - PAD;
        const float sc = scale[n];
        const int dx = x - x0;
        const bool okx = (unsigned)dx < 21u;        // only divergent condition
        const float* p = psf_raw + (size_t)n * PSF3 + dx;

#pragma unroll
        for (int zi = 0; zi < TZ; ++zi) {
            const int dz = zbase + zi - z0;
            if ((unsigned)dz < 21u) {               // block-uniform branch
#pragma unroll
                for (int j = 0; j < 2; ++j) {
                    const int dy = ybase + ysub + 4 * j - y0;
                    if ((unsigned)dy < 21u && okx) {   // wave-uniform + okx
                        float val = fmaxf(p[(dz * 21 + dy) * 21], 0.0f);
                        acc[zi][j] += sc * val;
                    }
                }
            }
        }
    }

    // coalesced write-out: covers every voxel exactly once (no memset needed)
    const size_t outbase = (((size_t)c * 256 + zbase) * 256) * 64;
#pragma unroll
    for (int zi = 0; zi < TZ; ++zi) {
#pragma unroll
        for (int j = 0; j < 2; ++j) {
            const int yg = ybase + ysub + 4 * j;
            out[outbase + (size_t)zi * 256 * 64 + (size_t)yg * 64 + x] = acc[zi][j];
        }
    }
}

extern "C" void kernel_launch(void* const* d_in, const int* in_sizes, int n_in,
                              void* d_out, int out_size, void* d_ws, size_t ws_size,
                              hipStream_t stream) {
    const float* psf_raw = (const float*)d_in[0];
    const float* i_val   = (const float*)d_in[1];
    const int*   bArr    = (const int*)d_in[2];
    const int*   chArr   = (const int*)d_in[3];
    const int*   zArr    = (const int*)d_in[4];
    const int*   yArr    = (const int*)d_in[5];
    const int*   xArr    = (const int*)d_in[6];
    float* out = (float*)d_out;

    const int N = in_sizes[1];   // 8192 points

    // workspace layout
    char* ws = (char*)d_ws;
    float* scale  = (float*)(ws + 0);            // 32 KB
    int*   cnt    = (int*)(ws + 32768);          // 64 KB
    int*   off    = (int*)(ws + 98304);          // 64 KB
    int*   cursor = (int*)(ws + 163840);         // 64 KB
    int*   list   = (int*)(ws + 229376);         // 512 KB (max 16 tiles/psf)

    hipMemsetAsync(cnt, 0, NTILES * sizeof(int), stream);

    psf_scale_kernel<<<N, 256, 0, stream>>>(psf_raw, i_val, scale);
    count_kernel<<<(N + 255) / 256, 256, 0, stream>>>(bArr, chArr, zArr, yArr, cnt, N);
    scan_kernel<<<1, 256, 0, stream>>>(cnt, off, cursor);
    fill_kernel<<<(N + 255) / 256, 256, 0, stream>>>(bArr, chArr, zArr, yArr, cursor, list, N);
    gather_kernel<<<NTILES, 256, 0, stream>>>(psf_raw, scale, zArr, yArr, xArr,
                                              off, cnt, list, out);
}

// Round 3
// 238.157 us; speedup vs baseline: 1.7597x; 1.7597x over previous
//
#include <hip/hip_runtime.h>

#define SCALE_F 10000.0f
#define PSF 21
#define PAD 10
#define PSF3 9261        // 21*21*21
#define NTILES 16384     // 16 channels * 32 * 32

// ---------------- scale pre-pass: per-PSF max -> packed meta ----------------
__global__ __launch_bounds__(256) void psf_scale_kernel(
    const float* __restrict__ psf_raw,
    const float* __restrict__ i_val,
    const int* __restrict__ zArr, const int* __restrict__ yArr,
    const int* __restrict__ xArr,
    int4*       __restrict__ meta)
{
    const int n   = blockIdx.x;
    const int tid = threadIdx.x;
    const float* p = psf_raw + (size_t)n * PSF3;

    float m = 0.0f;
    for (int k = tid; k < PSF3; k += 256)
        m = fmaxf(m, p[k]);          // relu'd max (m starts at 0)

#pragma unroll
    for (int off = 32; off > 0; off >>= 1)
        m = fmaxf(m, __shfl_down(m, off, 64));

    __shared__ float smax[4];
    if ((tid & 63) == 0) smax[tid >> 6] = m;
    __syncthreads();
    if (tid == 0) {
        float mm = fmaxf(fmaxf(smax[0], smax[1]), fmaxf(smax[2], smax[3]));
        float sc = (mm > 0.0f) ? SCALE_F * fmaxf(i_val[n], 0.0f) / mm : 0.0f;
        meta[n] = make_int4(zArr[n] - PAD, yArr[n] - PAD, xArr[n] - PAD,
                            __float_as_int(sc));
    }
}

// ---------------- binning ----------------
__device__ __forceinline__ void tile_range(int v0, int& lo, int& hi) {
    lo = max(v0, 0) >> 3;
    hi = min(v0 + 20, 255) >> 3;
}

__global__ __launch_bounds__(256) void count_kernel(
    const int* __restrict__ bArr, const int* __restrict__ chArr,
    const int* __restrict__ zArr, const int* __restrict__ yArr,
    int* __restrict__ cnt, int N)
{
    int n = blockIdx.x * 256 + threadIdx.x;
    if (n >= N) return;
    int c = bArr[n] * 16 + chArr[n];
    int tzlo, tzhi, tylo, tyhi;
    tile_range(zArr[n] - PAD, tzlo, tzhi);
    tile_range(yArr[n] - PAD, tylo, tyhi);
    for (int tz = tzlo; tz <= tzhi; ++tz)
        for (int ty = tylo; ty <= tyhi; ++ty)
            atomicAdd(&cnt[c * 1024 + tz * 32 + ty], 1);
}

__global__ __launch_bounds__(256) void scan_kernel(
    const int* __restrict__ cnt, int* __restrict__ off, int* __restrict__ cursor)
{
    __shared__ int s[256];
    __shared__ int base[256];
    const int t = threadIdx.x;
    const int b0 = t * 64;
    int local = 0;
    for (int i = 0; i < 64; ++i) local += cnt[b0 + i];
    s[t] = local;
    __syncthreads();
    if (t == 0) {
        int run = 0;
        for (int i = 0; i < 256; ++i) { base[i] = run; run += s[i]; }
    }
    __syncthreads();
    int run = base[t];
    for (int i = 0; i < 64; ++i) {
        int c = cnt[b0 + i];
        off[b0 + i] = run;
        cursor[b0 + i] = run;
        run += c;
    }
}

__global__ __launch_bounds__(256) void fill_kernel(
    const int* __restrict__ bArr, const int* __restrict__ chArr,
    const int* __restrict__ zArr, const int* __restrict__ yArr,
    int* __restrict__ cursor, int* __restrict__ list, int N)
{
    int n = blockIdx.x * 256 + threadIdx.x;
    if (n >= N) return;
    int c = bArr[n] * 16 + chArr[n];
    int tzlo, tzhi, tylo, tyhi;
    tile_range(zArr[n] - PAD, tzlo, tzhi);
    tile_range(yArr[n] - PAD, tylo, tyhi);
    for (int tz = tzlo; tz <= tzhi; ++tz)
        for (int ty = tylo; ty <= tyhi; ++ty) {
            int pos = atomicAdd(&cursor[c * 1024 + tz * 32 + ty], 1);
            list[pos] = n;
        }
}

// ---------------- gather: one block per (c, 8z, 8y, 64x) tile ----------------
// Branchless: all 16 slot-loads per pair use clamped in-bounds addresses and
// issue unconditionally (single batch, one waitcnt); validity applied via
// cndmask'd weight. n and meta fields forced to SGPR via readfirstlane.
__global__ __launch_bounds__(256) void gather_kernel(
    const float* __restrict__ psf_raw,
    const int4* __restrict__ meta,
    const int* __restrict__ off, const int* __restrict__ cnt,
    const int* __restrict__ list,
    float* __restrict__ out)
{
    const int tile = blockIdx.x;
    const int ty = tile & 31;
    const int tz = (tile >> 5) & 31;
    const int c  = tile >> 10;
    const int t  = threadIdx.x;
    const int x    = t & 63;
    const int ysub = t >> 6;          // wave id 0..3
    const int zbase = tz * 8;
    const int ybase = ty * 8;

    float acc0[8] = {};
    float acc1[8] = {};

    const int o  = off[tile];
    const int cn = cnt[tile];

    int nnext = (cn > 0) ? list[o] : 0;

    for (int i = 0; i < cn; ++i) {
        const int n = __builtin_amdgcn_readfirstlane(nnext);
        const int4 mt = meta[n];
        nnext = list[o + min(i + 1, cn - 1)];     // prefetch next pair

        const int z0 = __builtin_amdgcn_readfirstlane(mt.x);
        const int y0 = __builtin_amdgcn_readfirstlane(mt.y);
        const int x0 = __builtin_amdgcn_readfirstlane(mt.z);
        const float sc = __int_as_float(__builtin_amdgcn_readfirstlane(mt.w));

        const int dx  = x - x0;
        const bool okx = (unsigned)dx < 21u;
        const int dxc = min(max(dx, 0), 20);

        const int dy0 = ybase + ysub - y0;
        const int dy1 = dy0 + 4;
        const bool oky0 = okx & ((unsigned)dy0 < 21u);
        const bool oky1 = okx & ((unsigned)dy1 < 21u);
        const int row0 = min(max(dy0, 0), 20) * 21 + dxc;
        const int row1 = min(max(dy1, 0), 20) * 21 + dxc;

        const float* pb = psf_raw + (size_t)n * PSF3;

#pragma unroll
        for (int zi = 0; zi < 8; ++zi) {
            const int dz = zbase + zi - z0;                // scalar
            const bool okz = (unsigned)dz < 21u;
            const int zoff = (okz ? dz : 0) * 441;         // scalar clamp
            float v0 = pb[zoff + row0];
            float v1 = pb[zoff + row1];
            float w0 = (okz & oky0) ? sc : 0.0f;
            float w1 = (okz & oky1) ? sc : 0.0f;
            acc0[zi] += w0 * fmaxf(v0, 0.0f);
            acc1[zi] += w1 * fmaxf(v1, 0.0f);
        }
    }

    // coalesced write-out: covers every voxel exactly once (no memset needed)
    const size_t outbase = (((size_t)c * 256 + zbase) * 256 + ybase) * 64 + x;
#pragma unroll
    for (int zi = 0; zi < 8; ++zi) {
        out[outbase + (size_t)zi * (256 * 64) + (size_t)ysub * 64]       = acc0[zi];
        out[outbase + (size_t)zi * (256 * 64) + (size_t)(ysub + 4) * 64] = acc1[zi];
    }
}

extern "C" void kernel_launch(void* const* d_in, const int* in_sizes, int n_in,
                              void* d_out, int out_size, void* d_ws, size_t ws_size,
                              hipStream_t stream) {
    const float* psf_raw = (const float*)d_in[0];
    const float* i_val   = (const float*)d_in[1];
    const int*   bArr    = (const int*)d_in[2];
    const int*   chArr   = (const int*)d_in[3];
    const int*   zArr    = (const int*)d_in[4];
    const int*   yArr    = (const int*)d_in[5];
    const int*   xArr    = (const int*)d_in[6];
    float* out = (float*)d_out;

    const int N = in_sizes[1];   // 8192 points

    // workspace layout
    char* ws = (char*)d_ws;
    int4*  meta   = (int4*)(ws + 0);             // 128 KB
    int*   cnt    = (int*)(ws + 131072);         // 64 KB
    int*   off    = (int*)(ws + 196608);         // 64 KB
    int*   cursor = (int*)(ws + 262144);         // 64 KB
    int*   list   = (int*)(ws + 327680);         // 512 KB (max 16 tiles/psf)

    hipMemsetAsync(cnt, 0, NTILES * sizeof(int), stream);

    psf_scale_kernel<<<N, 256, 0, stream>>>(psf_raw, i_val, zArr, yArr, xArr, meta);
    count_kernel<<<(N + 255) / 256, 256, 0, stream>>>(bArr, chArr, zArr, yArr, cnt, N);
    scan_kernel<<<1, 256, 0, stream>>>(cnt, off, cursor);
    fill_kernel<<<(N + 255) / 256, 256, 0, stream>>>(bArr, chArr, zArr, yArr, cursor, list, N);
    gather_kernel<<<NTILES, 256, 0, stream>>>(psf_raw, meta, off, cnt, list, out);
}

// Round 4
// 201.227 us; speedup vs baseline: 2.0827x; 1.1835x over previous
//
#include <hip/hip_runtime.h>

#define SCALE_F 10000.0f
#define PSF 21
#define PAD 10
#define PSF3 9261        // 21*21*21
#define NTILES 16384     // 16 channels * 32 * 32

// ---------------- fused scale + count ----------------
// float4 main loop with alignment peel (psf base byte offset mod 16 = 4*(n&3)).
__global__ __launch_bounds__(256) void psf_scale_count_kernel(
    const float* __restrict__ psf_raw,
    const float* __restrict__ i_val,
    const int* __restrict__ bArr, const int* __restrict__ chArr,
    const int* __restrict__ zArr, const int* __restrict__ yArr,
    const int* __restrict__ xArr,
    int4* __restrict__ meta,
    int*  __restrict__ cnt)
{
    const int n   = blockIdx.x;
    const int tid = threadIdx.x;
    const float* p = psf_raw + (size_t)n * PSF3;

    const int peel = (4 - (n & 3)) & 3;        // elems until 16B alignment
    float m = 0.0f;
    if (tid < peel) m = fmaxf(m, p[tid]);
    const float4* p4 = (const float4*)(p + peel);
    const int nq = (PSF3 - peel) >> 2;         // 2314 or 2315 quads
    for (int k = tid; k < nq; k += 256) {
        float4 q = p4[k];
        m = fmaxf(m, fmaxf(fmaxf(q.x, q.y), fmaxf(q.z, q.w)));
    }
    const int rem = (PSF3 - peel) & 3;
    if (tid < rem) m = fmaxf(m, p[PSF3 - rem + tid]);

#pragma unroll
    for (int off = 32; off > 0; off >>= 1)
        m = fmaxf(m, __shfl_down(m, off, 64));

    __shared__ float smax[4];
    if ((tid & 63) == 0) smax[tid >> 6] = m;
    __syncthreads();
    if (tid == 0) {
        float mm = fmaxf(fmaxf(smax[0], smax[1]), fmaxf(smax[2], smax[3]));
        float sc = (mm > 0.0f) ? SCALE_F * fmaxf(i_val[n], 0.0f) / mm : 0.0f;
        int z0 = zArr[n] - PAD, y0 = yArr[n] - PAD, x0 = xArr[n] - PAD;
        meta[n] = make_int4(z0, y0, x0, __float_as_int(sc));
        // count bins (fused former count_kernel)
        int c = bArr[n] * 16 + chArr[n];
        int tzlo = max(z0, 0) >> 3, tzhi = min(z0 + 20, 255) >> 3;
        int tylo = max(y0, 0) >> 3, tyhi = min(y0 + 20, 255) >> 3;
        for (int tz = tzlo; tz <= tzhi; ++tz)
            for (int ty = tylo; ty <= tyhi; ++ty)
                atomicAdd(&cnt[c * 1024 + tz * 32 + ty], 1);
    }
}

// ---------------- register-resident exclusive scan (single block) ----------------
__global__ __launch_bounds__(256) void scan_kernel(
    const int4* __restrict__ cnt4, int4* __restrict__ off4, int4* __restrict__ cur4)
{
    const int t = threadIdx.x;
    int4 v[16];
#pragma unroll
    for (int i = 0; i < 16; ++i) v[i] = cnt4[t * 16 + i];
    int sum = 0;
#pragma unroll
    for (int i = 0; i < 16; ++i) sum += v[i].x + v[i].y + v[i].z + v[i].w;

    const int lane = t & 63, w = t >> 6;
    int s = sum;
#pragma unroll
    for (int d = 1; d < 64; d <<= 1) {
        int u = __shfl_up(s, d, 64);
        if (lane >= d) s += u;
    }
    __shared__ int wsum[4];
    if (lane == 63) wsum[w] = s;
    __syncthreads();
    int base = 0;
    for (int i = 0; i < w; ++i) base += wsum[i];
    int run = base + s - sum;       // exclusive prefix for this thread's chunk

#pragma unroll
    for (int i = 0; i < 16; ++i) {
        int4 o;
        o.x = run; run += v[i].x;
        o.y = run; run += v[i].y;
        o.z = run; run += v[i].z;
        o.w = run; run += v[i].w;
        off4[t * 16 + i] = o;
        cur4[t * 16 + i] = o;
    }
}

// ---------------- binning: fill ----------------
__global__ __launch_bounds__(256) void fill_kernel(
    const int* __restrict__ bArr, const int* __restrict__ chArr,
    const int* __restrict__ zArr, const int* __restrict__ yArr,
    int* __restrict__ cursor, int* __restrict__ list, int N)
{
    int n = blockIdx.x * 256 + threadIdx.x;
    if (n >= N) return;
    int c = bArr[n] * 16 + chArr[n];
    int z0 = zArr[n] - PAD, y0 = yArr[n] - PAD;
    int tzlo = max(z0, 0) >> 3, tzhi = min(z0 + 20, 255) >> 3;
    int tylo = max(y0, 0) >> 3, tyhi = min(y0 + 20, 255) >> 3;
    for (int tz = tzlo; tz <= tzhi; ++tz)
        for (int ty = tylo; ty <= tyhi; ++ty) {
            int pos = atomicAdd(&cursor[c * 1024 + tz * 32 + ty], 1);
            list[pos] = n;
        }
}

// ---------------- gather: one block per (c, 8z, 8y, 64x) tile ----------------
// y-row validity is wave-uniform (ysub = t>>6): branch into 3 paths OUTSIDE the
// unrolled z-loop so each path's loads still batch into one clause; z handled
// with scalar clamp + weight masking (keeps batching).
__global__ __launch_bounds__(256) void gather_kernel(
    const float* __restrict__ psf_raw,
    const int4* __restrict__ meta,
    const int* __restrict__ off, const int* __restrict__ cnt,
    const int* __restrict__ list,
    float* __restrict__ out)
{
    const int tile = blockIdx.x;
    const int ty = tile & 31;
    const int tz = (tile >> 5) & 31;
    const int c  = tile >> 10;
    const int t  = threadIdx.x;
    const int x    = t & 63;
    const int ysub = t >> 6;          // wave id 0..3
    const int zbase = tz * 8;
    const int ybase = ty * 8;

    float acc0[8] = {};
    float acc1[8] = {};

    const int o  = off[tile];
    const int cn = cnt[tile];

    int nnext = (cn > 0) ? list[o] : 0;

    for (int i = 0; i < cn; ++i) {
        const int n = __builtin_amdgcn_readfirstlane(nnext);
        const int4 mt = meta[n];
        nnext = list[o + min(i + 1, cn - 1)];     // prefetch next pair

        const int z0 = __builtin_amdgcn_readfirstlane(mt.x);
        const int y0 = __builtin_amdgcn_readfirstlane(mt.y);
        const int x0 = __builtin_amdgcn_readfirstlane(mt.z);
        const float sc = __int_as_float(__builtin_amdgcn_readfirstlane(mt.w));

        const int dx  = x - x0;
        const float wsc = ((unsigned)dx < 21u) ? sc : 0.0f;
        const int dxc = min(max(dx, 0), 20);

        const int dy0 = ybase + ysub - y0;        // wave-uniform value
        const int dy1 = dy0 + 4;
        const int a0 = __any((unsigned)dy0 < 21u);  // wave-uniform scalar
        const int a1 = __any((unsigned)dy1 < 21u);
        const int row0 = dy0 * 21 + dxc;
        const int row1 = dy1 * 21 + dxc;
        const float* pb = psf_raw + (size_t)n * PSF3;

        if (a0 & a1) {
#pragma unroll
            for (int zi = 0; zi < 8; ++zi) {
                const int dz = zbase + zi - z0;
                const int zo = min(max(dz, 0), 20) * 441;
                const float w = ((unsigned)dz < 21u) ? wsc : 0.0f;
                acc0[zi] += w * fmaxf(pb[zo + row0], 0.0f);
                acc1[zi] += w * fmaxf(pb[zo + row1], 0.0f);
            }
        } else if (a0) {
#pragma unroll
            for (int zi = 0; zi < 8; ++zi) {
                const int dz = zbase + zi - z0;
                const int zo = min(max(dz, 0), 20) * 441;
                const float w = ((unsigned)dz < 21u) ? wsc : 0.0f;
                acc0[zi] += w * fmaxf(pb[zo + row0], 0.0f);
            }
        } else if (a1) {
#pragma unroll
            for (int zi = 0; zi < 8; ++zi) {
                const int dz = zbase + zi - z0;
                const int zo = min(max(dz, 0), 20) * 441;
                const float w = ((unsigned)dz < 21u) ? wsc : 0.0f;
                acc1[zi] += w * fmaxf(pb[zo + row1], 0.0f);
            }
        }
    }

    // coalesced write-out: covers every voxel exactly once (no memset needed)
    const size_t outbase = (((size_t)c * 256 + zbase) * 256 + ybase) * 64 + x;
#pragma unroll
    for (int zi = 0; zi < 8; ++zi) {
        out[outbase + (size_t)zi * (256 * 64) + (size_t)ysub * 64]       = acc0[zi];
        out[outbase + (size_t)zi * (256 * 64) + (size_t)(ysub + 4) * 64] = acc1[zi];
    }
}

extern "C" void kernel_launch(void* const* d_in, const int* in_sizes, int n_in,
                              void* d_out, int out_size, void* d_ws, size_t ws_size,
                              hipStream_t stream) {
    const float* psf_raw = (const float*)d_in[0];
    const float* i_val   = (const float*)d_in[1];
    const int*   bArr    = (const int*)d_in[2];
    const int*   chArr   = (const int*)d_in[3];
    const int*   zArr    = (const int*)d_in[4];
    const int*   yArr    = (const int*)d_in[5];
    const int*   xArr    = (const int*)d_in[6];
    float* out = (float*)d_out;

    const int N = in_sizes[1];   // 8192 points

    // workspace layout
    char* ws = (char*)d_ws;
    int4*  meta   = (int4*)(ws + 0);             // 128 KB
    int*   cnt    = (int*)(ws + 131072);         // 64 KB
    int*   off    = (int*)(ws + 196608);         // 64 KB
    int*   cursor = (int*)(ws + 262144);         // 64 KB
    int*   list   = (int*)(ws + 327680);         // 512 KB (max 16 tiles/psf)

    hipMemsetAsync(cnt, 0, NTILES * sizeof(int), stream);

    psf_scale_count_kernel<<<N, 256, 0, stream>>>(psf_raw, i_val, bArr, chArr,
                                                  zArr, yArr, xArr, meta, cnt);
    scan_kernel<<<1, 256, 0, stream>>>((const int4*)cnt, (int4*)off, (int4*)cursor);
    fill_kernel<<<(N + 255) / 256, 256, 0, stream>>>(bArr, chArr, zArr, yArr, cursor, list, N);
    gather_kernel<<<NTILES, 256, 0, stream>>>(psf_raw, meta, off, cnt, list, out);
}

// Round 5
// 186.823 us; speedup vs baseline: 2.2433x; 1.0771x over previous
//
#include <hip/hip_runtime.h>

#define SCALE_F 10000.0f
#define PSF 21
#define PAD 10
#define PSF3 9261        // 21*21*21
#define NTILES 16384     // 16 channels * 32 * 32

// workspace layout (bytes)
#define META_OFF 0        // 8192 * 16 B   = 131072
#define CNT_OFF  131072   // 16384 * 4 B   = 65536
#define SCAN_OFF 196608   // 16384 * 4 B   (fallback only)
#define CUR_OFF  262144   // 16384 * 4 B   (fallback only)
#define LIST_OFF 327680   // capacity list (cap path) or exact list (fallback)

// ---------------- fused scale + bin(+fill) ----------------
// float4 main loop with alignment peel (psf base elem offset mod 4 = n&3).
// cap > 0: thread0 fills list[tile*cap + pos] directly (no scan needed).
// cap == 0: count-only (fallback path, exact scan binning follows).
__global__ __launch_bounds__(256) void psf_scale_fill_kernel(
    const float* __restrict__ psf_raw,
    const float* __restrict__ i_val,
    const int* __restrict__ bArr, const int* __restrict__ chArr,
    const int* __restrict__ zArr, const int* __restrict__ yArr,
    const int* __restrict__ xArr,
    int4* __restrict__ meta,
    int*  __restrict__ cnt,
    int*  __restrict__ list,
    int cap)
{
    const int n   = blockIdx.x;
    const int tid = threadIdx.x;
    const float* p = psf_raw + (size_t)n * PSF3;

    const int peel = (4 - (n & 3)) & 3;        // elems until 16B alignment
    float m = 0.0f;
    if (tid < peel) m = fmaxf(m, p[tid]);
    const float4* p4 = (const float4*)(p + peel);
    const int nq = (PSF3 - peel) >> 2;
    for (int k = tid; k < nq; k += 256) {
        float4 q = p4[k];
        m = fmaxf(m, fmaxf(fmaxf(q.x, q.y), fmaxf(q.z, q.w)));
    }
    const int rem = (PSF3 - peel) & 3;
    if (tid < rem) m = fmaxf(m, p[PSF3 - rem + tid]);

#pragma unroll
    for (int off = 32; off > 0; off >>= 1)
        m = fmaxf(m, __shfl_down(m, off, 64));

    __shared__ float smax[4];
    if ((tid & 63) == 0) smax[tid >> 6] = m;
    __syncthreads();
    if (tid == 0) {
        float mm = fmaxf(fmaxf(smax[0], smax[1]), fmaxf(smax[2], smax[3]));
        float sc = (mm > 0.0f) ? SCALE_F * fmaxf(i_val[n], 0.0f) / mm : 0.0f;
        int z0 = zArr[n] - PAD, y0 = yArr[n] - PAD, x0 = xArr[n] - PAD;
        meta[n] = make_int4(z0, y0, x0, __float_as_int(sc));
        int c = bArr[n] * 16 + chArr[n];
        int tzlo = max(z0, 0) >> 3, tzhi = min(z0 + 20, 255) >> 3;
        int tylo = max(y0, 0) >> 3, tyhi = min(y0 + 20, 255) >> 3;
        if (cap > 0) {
            for (int tz = tzlo; tz <= tzhi; ++tz)
                for (int ty = tylo; ty <= tyhi; ++ty) {
                    int t = c * 1024 + tz * 32 + ty;
                    int pos = atomicAdd(&cnt[t], 1);
                    if (pos < cap) list[t * cap + pos] = n;
                }
        } else {
            for (int tz = tzlo; tz <= tzhi; ++tz)
                for (int ty = tylo; ty <= tyhi; ++ty)
                    atomicAdd(&cnt[c * 1024 + tz * 32 + ty], 1);
        }
    }
}

// ---------------- fallback: register-resident exclusive scan ----------------
__global__ __launch_bounds__(256) void scan_kernel(
    const int4* __restrict__ cnt4, int4* __restrict__ off4, int4* __restrict__ cur4)
{
    const int t = threadIdx.x;
    int4 v[16];
#pragma unroll
    for (int i = 0; i < 16; ++i) v[i] = cnt4[t * 16 + i];
    int sum = 0;
#pragma unroll
    for (int i = 0; i < 16; ++i) sum += v[i].x + v[i].y + v[i].z + v[i].w;

    const int lane = t & 63, w = t >> 6;
    int s = sum;
#pragma unroll
    for (int d = 1; d < 64; d <<= 1) {
        int u = __shfl_up(s, d, 64);
        if (lane >= d) s += u;
    }
    __shared__ int wsum[4];
    if (lane == 63) wsum[w] = s;
    __syncthreads();
    int base = 0;
    for (int i = 0; i < w; ++i) base += wsum[i];
    int run = base + s - sum;

#pragma unroll
    for (int i = 0; i < 16; ++i) {
        int4 o;
        o.x = run; run += v[i].x;
        o.y = run; run += v[i].y;
        o.z = run; run += v[i].z;
        o.w = run; run += v[i].w;
        off4[t * 16 + i] = o;
        cur4[t * 16 + i] = o;
    }
}

// ---------------- fallback: fill ----------------
__global__ __launch_bounds__(256) void fill_kernel(
    const int* __restrict__ bArr, const int* __restrict__ chArr,
    const int* __restrict__ zArr, const int* __restrict__ yArr,
    int* __restrict__ cursor, int* __restrict__ list, int N)
{
    int n = blockIdx.x * 256 + threadIdx.x;
    if (n >= N) return;
    int c = bArr[n] * 16 + chArr[n];
    int z0 = zArr[n] - PAD, y0 = yArr[n] - PAD;
    int tzlo = max(z0, 0) >> 3, tzhi = min(z0 + 20, 255) >> 3;
    int tylo = max(y0, 0) >> 3, tyhi = min(y0 + 20, 255) >> 3;
    for (int tz = tzlo; tz <= tzhi; ++tz)
        for (int ty = tylo; ty <= tyhi; ++ty) {
            int pos = atomicAdd(&cursor[c * 1024 + tz * 32 + ty], 1);
            list[pos] = n;
        }
}

// ---------------- gather: one block per (c, 8z, 8y, 64x) tile ----------------
__global__ __launch_bounds__(256) void gather_kernel(
    const float* __restrict__ psf_raw,
    const int4* __restrict__ meta,
    const int* __restrict__ off, const int* __restrict__ cnt,
    const int* __restrict__ list,
    float* __restrict__ out,
    int cap)
{
    const int tile = blockIdx.x;
    const int ty = tile & 31;
    const int tz = (tile >> 5) & 31;
    const int c  = tile >> 10;
    const int t  = threadIdx.x;
    const int x    = t & 63;
    const int ysub = t >> 6;          // wave id 0..3
    const int zbase = tz * 8;
    const int ybase = ty * 8;

    float acc0[8] = {};
    float acc1[8] = {};

    int o, cn;
    if (cap > 0) { o = tile * cap; cn = min(cnt[tile], cap); }
    else         { o = off[tile];  cn = cnt[tile]; }

    int  nnext = (cn > 0) ? list[o] : 0;
    int4 mnext = (cn > 0) ? meta[nnext] : make_int4(0, 0, 0, 0);

    for (int i = 0; i < cn; ++i) {
        const int  n  = __builtin_amdgcn_readfirstlane(nnext);
        const int4 mt = mnext;
        const int  nj = list[o + min(i + 1, cn - 1)];  // prefetch list
        nnext = nj;
        mnext = meta[nj];                              // prefetch meta (used next iter)

        const int z0 = __builtin_amdgcn_readfirstlane(mt.x);
        const int y0 = __builtin_amdgcn_readfirstlane(mt.y);
        const int x0 = __builtin_amdgcn_readfirstlane(mt.z);
        const float sc = __int_as_float(__builtin_amdgcn_readfirstlane(mt.w));

        const int dx  = x - x0;
        const float wsc = ((unsigned)dx < 21u) ? sc : 0.0f;
        const int dxc = min(max(dx, 0), 20);

        const int dy0 = ybase + ysub - y0;          // wave-uniform value
        const int dy1 = dy0 + 4;
        const int a0 = __any((unsigned)dy0 < 21u);  // wave-uniform scalar
        const int a1 = __any((unsigned)dy1 < 21u);
        const int row0 = dy0 * 21 + dxc;
        const int row1 = dy1 * 21 + dxc;
        const float* pb = psf_raw + (size_t)n * PSF3;

        if (a0 & a1) {
#pragma unroll
            for (int zi = 0; zi < 8; ++zi) {
                const int dz = zbase + zi - z0;
                const int zo = min(max(dz, 0), 20) * 441;
                const float w = ((unsigned)dz < 21u) ? wsc : 0.0f;
                acc0[zi] += w * fmaxf(pb[zo + row0], 0.0f);
                acc1[zi] += w * fmaxf(pb[zo + row1], 0.0f);
            }
        } else if (a0) {
#pragma unroll
            for (int zi = 0; zi < 8; ++zi) {
                const int dz = zbase + zi - z0;
                const int zo = min(max(dz, 0), 20) * 441;
                const float w = ((unsigned)dz < 21u) ? wsc : 0.0f;
                acc0[zi] += w * fmaxf(pb[zo + row0], 0.0f);
            }
        } else if (a1) {
#pragma unroll
            for (int zi = 0; zi < 8; ++zi) {
                const int dz = zbase + zi - z0;
                const int zo = min(max(dz, 0), 20) * 441;
                const float w = ((unsigned)dz < 21u) ? wsc : 0.0f;
                acc1[zi] += w * fmaxf(pb[zo + row1], 0.0f);
            }
        }
    }

    // coalesced nontemporal write-out (don't evict PSF lines from L2/L3)
    const size_t outbase = (((size_t)c * 256 + zbase) * 256 + ybase) * 64 + x;
#pragma unroll
    for (int zi = 0; zi < 8; ++zi) {
        __builtin_nontemporal_store(acc0[zi],
            &out[outbase + (size_t)zi * (256 * 64) + (size_t)ysub * 64]);
        __builtin_nontemporal_store(acc1[zi],
            &out[outbase + (size_t)zi * (256 * 64) + (size_t)(ysub + 4) * 64]);
    }
}

extern "C" void kernel_launch(void* const* d_in, const int* in_sizes, int n_in,
                              void* d_out, int out_size, void* d_ws, size_t ws_size,
                              hipStream_t stream) {
    const float* psf_raw = (const float*)d_in[0];
    const float* i_val   = (const float*)d_in[1];
    const int*   bArr    = (const int*)d_in[2];
    const int*   chArr   = (const int*)d_in[3];
    const int*   zArr    = (const int*)d_in[4];
    const int*   yArr    = (const int*)d_in[5];
    const int*   xArr    = (const int*)d_in[6];
    float* out = (float*)d_out;

    const int N = in_sizes[1];   // 8192 points

    char* ws = (char*)d_ws;
    int4*  meta   = (int4*)(ws + META_OFF);
    int*   cnt    = (int*)(ws + CNT_OFF);
    int*   off    = (int*)(ws + SCAN_OFF);
    int*   cursor = (int*)(ws + CUR_OFF);
    int*   list   = (int*)(ws + LIST_OFF);

    // capacity for direct binning; 0 => exact scan fallback
    size_t avail = (ws_size > LIST_OFF) ? (ws_size - LIST_OFF) : 0;
    size_t cap_s = avail / ((size_t)NTILES * sizeof(int));
    int cap = (cap_s >= 64) ? 64 : (int)cap_s;
    if (cap < 24) cap = 0;   // too risky / too small -> exact path

    hipMemsetAsync(cnt, 0, NTILES * sizeof(int), stream);

    psf_scale_fill_kernel<<<N, 256, 0, stream>>>(psf_raw, i_val, bArr, chArr,
                                                 zArr, yArr, xArr, meta, cnt, list, cap);
    if (cap == 0) {
        scan_kernel<<<1, 256, 0, stream>>>((const int4*)cnt, (int4*)off, (int4*)cursor);
        fill_kernel<<<(N + 255) / 256, 256, 0, stream>>>(bArr, chArr, zArr, yArr,
                                                         cursor, list, N);
    }
    gather_kernel<<<NTILES, 256, 0, stream>>>(psf_raw, meta, off, cnt, list, out, cap);
}

// Round 7
// 168.618 us; speedup vs baseline: 2.4855x; 1.1080x over previous
//
#include <hip/hip_runtime.h>
#include <hip/hip_fp16.h>

#define SCALE_F 10000.0f
#define PSF 21
#define PAD 10
#define PSF3 9261        // 21*21*21
#define PSF3P 9280       // padded fp16 stride (even; 9280*2B = 290 cache lines)
#define NTILES 16384     // 16 channels * 32 * 32
#define CAP 64

typedef float f32x4 __attribute__((ext_vector_type(4)));

// workspace layout (bytes)
#define META_OFF 0                 // 8192*16 = 131072
#define CNT_OFF  131072            // 16384*4 = 65536
#define SCAN_OFF 196608            // 16384*4 (fallback)
#define CUR_OFF  262144            // 16384*4 (fallback)
#define LIST_OFF 327680            // cap list (CAP*16384*4 = 4 MB) or exact list
#define PSC_OFF  4521984           // 256-aligned; + 32B slack + 8192*9280*2 B

// ---------------- fused scale (+fp16 materialize) + bin/fill ----------------
template<bool F16>
__global__ __launch_bounds__(256) void psf_scale_fill_kernel(
    const float* __restrict__ psf_raw,
    const float* __restrict__ i_val,
    const int* __restrict__ bArr, const int* __restrict__ chArr,
    const int* __restrict__ zArr, const int* __restrict__ yArr,
    const int* __restrict__ xArr,
    int4* __restrict__ meta,
    int*  __restrict__ cnt,
    int*  __restrict__ list,
    int cap,
    __half* __restrict__ pscaled)   // base (+16 halfs slack applied by host)
{
    const int n   = blockIdx.x;
    const int tid = threadIdx.x;
    const float* p = psf_raw + (size_t)n * PSF3;

    const int peel = (4 - (n & 3)) & 3;        // elems until 16B alignment
    const f32x4* p4 = (const f32x4*)(p + peel);
    const int nq  = (PSF3 - peel) >> 2;        // 2314 or 2315 quads
    const int rem = (PSF3 - peel) & 3;

    float head = 0.0f, tailv = 0.0f;
    if (tid < peel) head  = p[tid];
    if (tid < rem)  tailv = p[PSF3 - rem + tid];

    f32x4 q[10];
    float m = fmaxf(fmaxf(head, tailv), 0.0f);
#pragma unroll
    for (int j = 0; j < 10; ++j) {
        const int k = tid + (j << 8);
        if (j < 9 || k < nq) {                 // j<9 always in range
            f32x4 v = __builtin_nontemporal_load(p4 + k);
            q[j] = v;
            m = fmaxf(m, fmaxf(fmaxf(v.x, v.y), fmaxf(v.z, v.w)));
        } else {
            q[j] = (f32x4)(0.0f);
        }
    }

#pragma unroll
    for (int off = 32; off > 0; off >>= 1)
        m = fmaxf(m, __shfl_down(m, off, 64));

    __shared__ float smax[4];
    if ((tid & 63) == 0) smax[tid >> 6] = m;
    __syncthreads();
    const float mm = fmaxf(fmaxf(smax[0], smax[1]), fmaxf(smax[2], smax[3]));
    const float sc = (mm > 0.0f) ? SCALE_F * fmaxf(i_val[n], 0.0f) / mm : 0.0f;

    if (F16) {
        // store pre-scaled, pre-ReLU fp16 at position idx-peel (8B-aligned quads)
        __half* pb = pscaled + (size_t)n * PSF3P;
        if (tid < peel)
            pb[tid - peel] = __float2half_rn(sc * fmaxf(head, 0.0f));
        if (tid < rem)
            pb[PSF3 - rem + tid - peel] = __float2half_rn(sc * fmaxf(tailv, 0.0f));
        ushort4* pq = (ushort4*)pb;            // n*PSF3P divisible by 4
#pragma unroll
        for (int j = 0; j < 10; ++j) {
            const int k = tid + (j << 8);
            if (j < 9 || k < nq) {
                ushort4 u;
                u.x = __half_as_ushort(__float2half_rn(sc * fmaxf(q[j].x, 0.0f)));
                u.y = __half_as_ushort(__float2half_rn(sc * fmaxf(q[j].y, 0.0f)));
                u.z = __half_as_ushort(__float2half_rn(sc * fmaxf(q[j].z, 0.0f)));
                u.w = __half_as_ushort(__float2half_rn(sc * fmaxf(q[j].w, 0.0f)));
                pq[k] = u;
            }
        }
    }

    if (tid == 0) {
        int z0 = zArr[n] - PAD, y0 = yArr[n] - PAD, x0 = xArr[n] - PAD;
        meta[n] = make_int4(z0, y0, x0, __float_as_int(sc));
        int c = bArr[n] * 16 + chArr[n];
        int tzlo = max(z0, 0) >> 3, tzhi = min(z0 + 20, 255) >> 3;
        int tylo = max(y0, 0) >> 3, tyhi = min(y0 + 20, 255) >> 3;
        if (cap > 0) {
            for (int tz = tzlo; tz <= tzhi; ++tz)
                for (int ty = tylo; ty <= tyhi; ++ty) {
                    int t = c * 1024 + tz * 32 + ty;
                    int pos = atomicAdd(&cnt[t], 1);
                    if (pos < cap) list[t * cap + pos] = n;
                }
        } else {
            for (int tz = tzlo; tz <= tzhi; ++tz)
                for (int ty = tylo; ty <= tyhi; ++ty)
                    atomicAdd(&cnt[c * 1024 + tz * 32 + ty], 1);
        }
    }
}

// ---------------- fallback: register-resident exclusive scan ----------------
__global__ __launch_bounds__(256) void scan_kernel(
    const int4* __restrict__ cnt4, int4* __restrict__ off4, int4* __restrict__ cur4)
{
    const int t = threadIdx.x;
    int4 v[16];
#pragma unroll
    for (int i = 0; i < 16; ++i) v[i] = cnt4[t * 16 + i];
    int sum = 0;
#pragma unroll
    for (int i = 0; i < 16; ++i) sum += v[i].x + v[i].y + v[i].z + v[i].w;

    const int lane = t & 63, w = t >> 6;
    int s = sum;
#pragma unroll
    for (int d = 1; d < 64; d <<= 1) {
        int u = __shfl_up(s, d, 64);
        if (lane >= d) s += u;
    }
    __shared__ int wsum[4];
    if (lane == 63) wsum[w] = s;
    __syncthreads();
    int base = 0;
    for (int i = 0; i < w; ++i) base += wsum[i];
    int run = base + s - sum;

#pragma unroll
    for (int i = 0; i < 16; ++i) {
        int4 o;
        o.x = run; run += v[i].x;
        o.y = run; run += v[i].y;
        o.z = run; run += v[i].z;
        o.w = run; run += v[i].w;
        off4[t * 16 + i] = o;
        cur4[t * 16 + i] = o;
    }
}

// ---------------- fallback: fill ----------------
__global__ __launch_bounds__(256) void fill_kernel(
    const int* __restrict__ bArr, const int* __restrict__ chArr,
    const int* __restrict__ zArr, const int* __restrict__ yArr,
    int* __restrict__ cursor, int* __restrict__ list, int N)
{
    int n = blockIdx.x * 256 + threadIdx.x;
    if (n >= N) return;
    int c = bArr[n] * 16 + chArr[n];
    int z0 = zArr[n] - PAD, y0 = yArr[n] - PAD;
    int tzlo = max(z0, 0) >> 3, tzhi = min(z0 + 20, 255) >> 3;
    int tylo = max(y0, 0) >> 3, tyhi = min(y0 + 20, 255) >> 3;
    for (int tz = tzlo; tz <= tzhi; ++tz)
        for (int ty = tylo; ty <= tyhi; ++ty) {
            int pos = atomicAdd(&cursor[c * 1024 + tz * 32 + ty], 1);
            list[pos] = n;
        }
}

// ---------------- gather: one block per (c, 8z, 8y, 64x) tile ----------------
template<bool F16>
__global__ __launch_bounds__(256) void gather_kernel(
    const float* __restrict__ psf_raw,
    const __half* __restrict__ pscaled,
    const int4* __restrict__ meta,
    const int* __restrict__ off, const int* __restrict__ cnt,
    const int* __restrict__ list,
    float* __restrict__ out,
    int cap)
{
    const int tile = blockIdx.x;
    const int ty = tile & 31;
    const int tz = (tile >> 5) & 31;
    const int c  = tile >> 10;
    const int t  = threadIdx.x;
    const int x    = t & 63;
    const int ysub = t >> 6;          // wave id 0..3
    const int zbase = tz * 8;
    const int ybase = ty * 8;

    float acc0[8] = {};
    float acc1[8] = {};

    int o, cn;
    if (cap > 0) { o = tile * cap; cn = min(cnt[tile], cap); }
    else         { o = off[tile];  cn = cnt[tile]; }

    int  nnext = (cn > 0) ? list[o] : 0;
    int4 mnext = (cn > 0) ? meta[nnext] : make_int4(0, 0, 0, 0);

    for (int i = 0; i < cn; ++i) {
        const int  n  = __builtin_amdgcn_readfirstlane(nnext);
        const int4 mt = mnext;
        const int  nj = list[o + min(i + 1, cn - 1)];  // prefetch list
        nnext = nj;
        mnext = meta[nj];                              // prefetch meta

        const int z0 = __builtin_amdgcn_readfirstlane(mt.x);
        const int y0 = __builtin_amdgcn_readfirstlane(mt.y);
        const int x0 = __builtin_amdgcn_readfirstlane(mt.z);
        const float sc = __int_as_float(__builtin_amdgcn_readfirstlane(mt.w));

        const int dx  = x - x0;
        const float wsc = ((unsigned)dx < 21u) ? (F16 ? 1.0f : sc) : 0.0f;
        const int dxc = min(max(dx, 0), 20);

        const int dy0 = ybase + ysub - y0;          // wave-uniform value
        const int dy1 = dy0 + 4;
        const int a0 = __any((unsigned)dy0 < 21u);  // wave-uniform scalar
        const int a1 = __any((unsigned)dy1 < 21u);
        const int row0 = dy0 * 21 + dxc;
        const int row1 = dy1 * 21 + dxc;

        const float*  pbf = psf_raw + (size_t)n * PSF3;
        const __half* pbh = pscaled + (size_t)n * PSF3P - ((4 - (n & 3)) & 3);

        if (a0 & a1) {
#pragma unroll
            for (int zi = 0; zi < 8; ++zi) {
                const int dz = zbase + zi - z0;
                const int zo = min(max(dz, 0), 20) * 441;
                const float w = ((unsigned)dz < 21u) ? wsc : 0.0f;
                float v0 = F16 ? __half2float(pbh[zo + row0]) : fmaxf(pbf[zo + row0], 0.0f);
                float v1 = F16 ? __half2float(pbh[zo + row1]) : fmaxf(pbf[zo + row1], 0.0f);
                acc0[zi] += w * v0;
                acc1[zi] += w * v1;
            }
        } else if (a0) {
#pragma unroll
            for (int zi = 0; zi < 8; ++zi) {
                const int dz = zbase + zi - z0;
                const int zo = min(max(dz, 0), 20) * 441;
                const float w = ((unsigned)dz < 21u) ? wsc : 0.0f;
                float v0 = F16 ? __half2float(pbh[zo + row0]) : fmaxf(pbf[zo + row0], 0.0f);
                acc0[zi] += w * v0;
            }
        } else if (a1) {
#pragma unroll
            for (int zi = 0; zi < 8; ++zi) {
                const int dz = zbase + zi - z0;
                const int zo = min(max(dz, 0), 20) * 441;
                const float w = ((unsigned)dz < 21u) ? wsc : 0.0f;
                float v1 = F16 ? __half2float(pbh[zo + row1]) : fmaxf(pbf[zo + row1], 0.0f);
                acc1[zi] += w * v1;
            }
        }
    }

    // coalesced nontemporal write-out
    const size_t outbase = (((size_t)c * 256 + zbase) * 256 + ybase) * 64 + x;
#pragma unroll
    for (int zi = 0; zi < 8; ++zi) {
        __builtin_nontemporal_store(acc0[zi],
            &out[outbase + (size_t)zi * (256 * 64) + (size_t)ysub * 64]);
        __builtin_nontemporal_store(acc1[zi],
            &out[outbase + (size_t)zi * (256 * 64) + (size_t)(ysub + 4) * 64]);
    }
}

extern "C" void kernel_launch(void* const* d_in, const int* in_sizes, int n_in,
                              void* d_out, int out_size, void* d_ws, size_t ws_size,
                              hipStream_t stream) {
    const float* psf_raw = (const float*)d_in[0];
    const float* i_val   = (const float*)d_in[1];
    const int*   bArr    = (const int*)d_in[2];
    const int*   chArr   = (const int*)d_in[3];
    const int*   zArr    = (const int*)d_in[4];
    const int*   yArr    = (const int*)d_in[5];
    const int*   xArr    = (const int*)d_in[6];
    float* out = (float*)d_out;

    const int N = in_sizes[1];   // 8192 points

    char* ws = (char*)d_ws;
    int4*   meta    = (int4*)(ws + META_OFF);
    int*    cnt     = (int*)(ws + CNT_OFF);
    int*    offp    = (int*)(ws + SCAN_OFF);
    int*    cursor  = (int*)(ws + CUR_OFF);
    int*    list    = (int*)(ws + LIST_OFF);
    __half* pscaled = (__half*)(ws + PSC_OFF) + 16;   // 32B front slack

    // path selection by available workspace
    const size_t psc_need = (size_t)PSC_OFF + 64 + (size_t)N * PSF3P * 2;
    bool f16 = (ws_size >= psc_need);
    int cap;
    if (ws_size >= (size_t)LIST_OFF + (size_t)CAP * NTILES * 4) {
        cap = CAP;
    } else {
        size_t avail = (ws_size > LIST_OFF) ? ws_size - LIST_OFF : 0;
        size_t cap_s = avail / ((size_t)NTILES * sizeof(int));
        cap = (cap_s >= 24) ? (int)((cap_s < 64) ? cap_s : 64) : 0;
    }
    if (cap == 0) f16 = false;

    (void)hipMemsetAsync(cnt, 0, NTILES * sizeof(int), stream);

    if (f16)
        psf_scale_fill_kernel<true><<<N, 256, 0, stream>>>(psf_raw, i_val, bArr, chArr,
            zArr, yArr, xArr, meta, cnt, list, cap, pscaled);
    else
        psf_scale_fill_kernel<false><<<N, 256, 0, stream>>>(psf_raw, i_val, bArr, chArr,
            zArr, yArr, xArr, meta, cnt, list, cap, pscaled);

    if (cap == 0) {
        scan_kernel<<<1, 256, 0, stream>>>((const int4*)cnt, (int4*)offp, (int4*)cursor);
        fill_kernel<<<(N + 255) / 256, 256, 0, stream>>>(bArr, chArr, zArr, yArr,
                                                         cursor, list, N);
    }

    if (f16)
        gather_kernel<true><<<NTILES, 256, 0, stream>>>(psf_raw, pscaled, meta,
            offp, cnt, list, out, cap);
    else
        gather_kernel<false><<<NTILES, 256, 0, stream>>>(psf_raw, pscaled, meta,
            offp, cnt, list, out, cap);
}